// Round 2
// baseline (16529.347 us; speedup 1.0000x reference)
//
#include <hip/hip_runtime.h>
#include <stdint.h>

#define B_ 16
#define T_ 64
#define IN_ 1024
#define R_ 4096
#define A_ 18
#define H_ 1024
#define NC_ 32
#define NK_ 32
#define LAT_ 1024
#define NB_ 8
#define BS_ 512
#define FULL_ 5120
#define GIN_ 5138
#define G3_ 1536
#define NG_ 12288   // NB_*G3_

#define FULLS0 0
#define RECS0 5242880            // B*T*FULL
#define POST0 9437184            // + B*T*R
#define PRIOR0 10485760          // + B*T*LAT

#define KS1 64   // posterior mlp layer1 splits: K=5120, chunk 80
#define KC1 80
#define KS2 64   // posterior mlp layer2 splits: K=1024, chunk 16
#define KC2 16
#define NSP 19   // GRU partial splits: 16 gwih + 2 gwhh + 1 latent/act

// ---------------- threefry2x32 (JAX-exact) ----------------
__device__ __forceinline__ uint32_t rotl32(uint32_t v, int r){ return (v<<r)|(v>>(32-r)); }

__device__ __forceinline__ void tf2x32(uint32_t k0, uint32_t k1, uint32_t x0, uint32_t x1,
                                       uint32_t& o0, uint32_t& o1){
  uint32_t ks0=k0, ks1=k1, ks2=k0^k1^0x1BD11BDAu;
  x0+=ks0; x1+=ks1;
  x0+=x1; x1=rotl32(x1,13); x1^=x0;
  x0+=x1; x1=rotl32(x1,15); x1^=x0;
  x0+=x1; x1=rotl32(x1,26); x1^=x0;
  x0+=x1; x1=rotl32(x1, 6); x1^=x0;
  x0+=ks1; x1+=ks2+1u;
  x0+=x1; x1=rotl32(x1,17); x1^=x0;
  x0+=x1; x1=rotl32(x1,29); x1^=x0;
  x0+=x1; x1=rotl32(x1,16); x1^=x0;
  x0+=x1; x1=rotl32(x1,24); x1^=x0;
  x0+=ks2; x1+=ks0+2u;
  x0+=x1; x1=rotl32(x1,13); x1^=x0;
  x0+=x1; x1=rotl32(x1,15); x1^=x0;
  x0+=x1; x1=rotl32(x1,26); x1^=x0;
  x0+=x1; x1=rotl32(x1, 6); x1^=x0;
  x0+=ks0; x1+=ks1+3u;
  x0+=x1; x1=rotl32(x1,17); x1^=x0;
  x0+=x1; x1=rotl32(x1,29); x1^=x0;
  x0+=x1; x1=rotl32(x1,16); x1^=x0;
  x0+=x1; x1=rotl32(x1,24); x1^=x0;
  x0+=ks1; x1+=ks2+4u;
  x0+=x1; x1=rotl32(x1,13); x1^=x0;
  x0+=x1; x1=rotl32(x1,15); x1^=x0;
  x0+=x1; x1=rotl32(x1,26); x1^=x0;
  x0+=x1; x1=rotl32(x1, 6); x1^=x0;
  x0+=ks2; x1+=ks0+5u;
  o0=x0; o1=x1;
}

__global__ __launch_bounds__(256) void gumbel_init(float* __restrict__ gum){
  int g = blockIdx.x*256 + threadIdx.x;     // 64 * 16384
  int t = g >> 14, i = g & 16383;
  uint32_t k0t, k1t, o0, o1;
  tf2x32(0u, 1u, 0u, (uint32_t)t, k0t, k1t);
  tf2x32(k0t, k1t, 0u, (uint32_t)i, o0, o1);
  uint32_t bits = o0 ^ o1;
  uint32_t fb = (bits >> 9) | 0x3f800000u;
  float f = __uint_as_float(fb) - 1.0f;
  const float tiny = 1.17549435e-38f;
  float u = fmaxf(tiny, f + tiny);
  gum[g] = -logf(-logf(u));
}

// ---------------- per-step kernels ----------------

// layer1 of posterior MLP: x = [h, obs_t] (16 x 5120) @ pw1 (5120 x 1024) -> p1 partials
// grid (4 ct, 64 ks); 1 col/thread
__global__ __launch_bounds__(256) void mlp1_gemv(const float* __restrict__ pw1,
    const float* __restrict__ h, const float* __restrict__ obs, int t,
    float* __restrict__ p1){
  int ct = blockIdx.x, ks = blockIdx.y, tid = threadIdx.x;
  int col = ct*256 + tid;
  int k0 = ks*KC1;
  __shared__ float xs[KC1*16];
  for (int i = tid; i < KC1*16; i += 256){
    int kk = i >> 4, m = i & 15;
    int k = k0 + kk;
    xs[i] = (k < R_) ? h[m*R_ + k] : obs[((m*T_)+t)*IN_ + (k - R_)];
  }
  __syncthreads();
  float acc[16];
  #pragma unroll
  for (int m=0;m<16;m++) acc[m]=0.f;
  const float* w = pw1 + (size_t)k0*H_ + col;
  #pragma unroll 8
  for (int kk=0; kk<KC1; kk++){
    float wv = w[0];
    w += H_;
    #pragma unroll
    for (int m=0;m<16;m++) acc[m] = fmaf(xs[kk*16+m], wv, acc[m]);
  }
  float* o = p1 + (size_t)ks*B_*H_ + col;
  #pragma unroll
  for (int m=0;m<16;m++) o[(size_t)m*H_] = acc[m];
}

// fused: reduce p1 slice + silu -> hidden slice in LDS; then GEMV over pw2 rows
// grid (2 ct, 64 ks); chunk KC2=16 rows; 2 cols/thread (float2)
__global__ __launch_bounds__(256) void mlp2_fused(const float* __restrict__ p1,
    const float* __restrict__ pb1, const float* __restrict__ pw2,
    float* __restrict__ p2){
  int ct = blockIdx.x, ks = blockIdx.y, tid = threadIdx.x;
  int k0 = ks*KC2;
  __shared__ float hs[KC2*16];   // [kk][b]
  {
    int k = tid & 15, b = tid >> 4;    // one (k,b) pair per thread
    float v = pb1[k0 + k];
    #pragma unroll 8
    for (int s=0;s<KS1;s++) v += p1[((size_t)s*B_ + b)*H_ + k0 + k];
    float sg = 1.f/(1.f + expf(-v));
    hs[k*16 + b] = v * sg;
  }
  __syncthreads();
  int col = ct*512 + tid*2;
  float a0[16], a1[16];
  #pragma unroll
  for (int m=0;m<16;m++){ a0[m]=0.f; a1[m]=0.f; }
  const float* w = pw2 + (size_t)k0*H_ + col;
  #pragma unroll
  for (int kk=0; kk<KC2; kk++){
    float2 wv = *(const float2*)w;
    w += H_;
    #pragma unroll
    for (int m=0;m<16;m++){
      float x = hs[kk*16+m];
      a0[m] = fmaf(x, wv.x, a0[m]);
      a1[m] = fmaf(x, wv.y, a1[m]);
    }
  }
  float* o = p2 + (size_t)ks*B_*H_ + col;
  #pragma unroll
  for (int m=0;m<16;m++){ float2 st; st.x=a0[m]; st.y=a1[m]; *(float2*)(o + (size_t)m*H_) = st; }
}

// reduce logits, gumbel-argmax sample, one-hot into fulls, post log-softmax, idx
__global__ __launch_bounds__(256) void sample_kernel(const float* __restrict__ p2,
    const float* __restrict__ pb2, const float* __restrict__ gum, int t,
    float* __restrict__ dout, int* __restrict__ idxb){
  int b = blockIdx.x, tid = threadIdx.x;
  __shared__ float lg[1024];
  for (int c = tid; c < 1024; c += 256){
    float v = pb2[c];
    #pragma unroll 8
    for (int s=0;s<KS2;s++) v += p2[((size_t)s*B_ + b)*H_ + c];
    lg[c] = v;
  }
  __syncthreads();
  int lane = tid & 31;
  int grp = tid >> 5;    // 8 groups of 32 lanes
  size_t bt = (size_t)b*T_ + t;
  for (int rep=0; rep<4; rep++){
    int nc = rep*8 + grp;
    float l = lg[nc*32 + lane];
    float g = gum[((size_t)t << 14) + (size_t)b*1024 + nc*32 + lane];
    float y = l + g;
    int widx = lane; float wy = y;
    #pragma unroll
    for (int off=16; off>0; off>>=1){
      float oy = __shfl_xor(wy, off, 32);
      int   oi = __shfl_xor(widx, off, 32);
      if (oy > wy || (oy == wy && oi < widx)){ wy = oy; widx = oi; }
    }
    float mx = l;
    #pragma unroll
    for (int off=16; off>0; off>>=1) mx = fmaxf(mx, __shfl_xor(mx, off, 32));
    float e = expf(l - mx);
    float s = e;
    #pragma unroll
    for (int off=16; off>0; off>>=1) s += __shfl_xor(s, off, 32);
    float ls = logf(s);
    dout[POST0 + (bt*NC_ + nc)*NK_ + lane] = (l - mx) - ls;
    dout[FULLS0 + bt*FULL_ + R_ + nc*32 + lane] = (lane == widx) ? 1.0f : 0.0f;
    if (lane == 0) idxb[b*32 + nc] = widx;
  }
}

// unified GRU GEMV: 912 blocks = n(8) x ct(6, 256 cols) x role(19)
// role 0..15: gwih h-part chunk of 256 rows
// role 16,17: gwhh chunk of 256 rows
// role 18: latent one-hot gather (512 rows) + action rows (18)
__global__ __launch_bounds__(256) void gru_unified(const float* __restrict__ gwih,
    const float* __restrict__ gwhh, const float* __restrict__ h,
    const int* __restrict__ idxb, const float* __restrict__ act, int t,
    float* __restrict__ pg){
  __shared__ float xs[256*16];       // 16 KB
  int bid = blockIdx.x, tid = threadIdx.x;
  int n = bid / 114, rem = bid % 114;
  int ct = rem / NSP, role = rem % NSP;
  int col = ct*256 + tid;
  float acc[16];
  #pragma unroll
  for (int m=0;m<16;m++) acc[m]=0.f;

  if (role < 16){
    int k0 = role*256;
    for (int i = tid; i < 256*16; i += 256){
      int kk = i >> 4, m = i & 15;
      xs[i] = h[m*R_ + k0 + kk];
    }
    __syncthreads();
    const float* w = gwih + ((size_t)n*GIN_ + k0)*G3_ + col;
    #pragma unroll 8
    for (int kk=0; kk<256; kk++){
      float wv = w[0];
      w += G3_;
      #pragma unroll
      for (int m=0;m<16;m++) acc[m] = fmaf(xs[kk*16+m], wv, acc[m]);
    }
  } else if (role < 18){
    int k0 = (role-16)*256;
    for (int i = tid; i < 256*16; i += 256){
      int kk = i >> 4, m = i & 15;
      xs[i] = h[m*R_ + n*BS_ + k0 + kk];
    }
    __syncthreads();
    const float* w = gwhh + ((size_t)n*BS_ + k0)*G3_ + col;
    #pragma unroll 8
    for (int kk=0; kk<256; kk++){
      float wv = w[0];
      w += G3_;
      #pragma unroll
      for (int m=0;m<16;m++) acc[m] = fmaf(xs[kk*16+m], wv, acc[m]);
    }
  } else {
    __shared__ int idxs[512];
    __shared__ float as_[16*18];
    for (int i = tid; i < 512; i += 256) idxs[i] = idxb[i];
    for (int i = tid; i < 16*18; i += 256){
      int m = i/18, a = i%18;
      as_[i] = act[((m*T_)+t)*A_ + a];
    }
    __syncthreads();
    const float* wb = gwih + (size_t)n*GIN_*G3_ + col;
    #pragma unroll 4
    for (int p=0; p<512; p++){
      int b = p >> 5, nc = p & 31;
      size_t row = (size_t)(R_ + nc*32 + idxs[b*32 + nc]);
      acc[b] += wb[row*G3_];
    }
    for (int a=0; a<18; a++){
      float wv = wb[(size_t)(R_+LAT_+a)*G3_];
      #pragma unroll
      for (int m=0;m<16;m++) acc[m] = fmaf(as_[m*18+a], wv, acc[m]);
    }
  }
  float* o = pg + ((size_t)role*B_)*NG_ + (size_t)n*G3_ + col;
  #pragma unroll
  for (int m=0;m<16;m++) o[(size_t)m*NG_] = acc[m];
}

// reduce pg splits, apply GRU gates, update h, write h_t into recs & fulls
__global__ __launch_bounds__(256) void gate_kernel(const float* __restrict__ pg,
    const float* __restrict__ gbih, const float* __restrict__ gbhh,
    const float* __restrict__ h_old, float* __restrict__ h_new,
    const int* __restrict__ dones, int t, float* __restrict__ dout){
  int g = blockIdx.x*256 + threadIdx.x;  // 65536
  int b = g >> 12, j = g & 4095;
  int n = j >> 9, u = j & 511;
  float rs = gbih[n*G3_ + u] + gbhh[n*G3_ + u];
  float zs = gbih[n*G3_ + 512 + u] + gbhh[n*G3_ + 512 + u];
  float ns_x = gbih[n*G3_ + 1024 + u];
  float ns_h = gbhh[n*G3_ + 1024 + u];
  // splits 0..15 + 18 are "x" contributions; 16,17 are "h" contributions.
  // r and z gates only need the total sum; n gate needs x and h parts separate.
  #pragma unroll
  for (int s=0;s<NSP;s++){
    const float* p = pg + ((size_t)s*B_ + b)*NG_ + (size_t)n*G3_;
    rs += p[u]; zs += p[512+u];
    float nv = p[1024+u];
    if (s == 16 || s == 17) ns_h += nv; else ns_x += nv;
  }
  float rr = 1.f/(1.f + expf(-rs));
  float zz = 1.f/(1.f + expf(-zs));
  float nn = tanhf(ns_x + rr*ns_h);
  float hold = h_old[g];
  float hnew = (1.f - zz)*nn + zz*hold;
  float nd = 1.f - (float)dones[b*T_ + t];
  h_new[g] = hnew * nd;
  size_t bt = (size_t)b*T_ + t;
  dout[FULLS0 + bt*FULL_ + j] = hold;
  dout[RECS0 + bt*(size_t)R_ + j] = hold;
}

// ---------------- prior MLP (batch GEMM at end) ----------------
// 128 threads, 64x64 tile, 4 rows x 8 cols per thread (FMA-bound)
template<int ACT>
__global__ __launch_bounds__(128) void gemm_tiled(const float* __restrict__ Aa,
    const float* __restrict__ W, const float* __restrict__ bias,
    float* __restrict__ out, int M, int N, int K){
  __shared__ float As[16][68];
  __shared__ float Bs[16][64];
  int bx = blockIdx.x, by = blockIdx.y, tid = threadIdx.x;
  int tx = tid & 7, ty = tid >> 3;       // tx: 8 col-groups, ty: 16 row-groups
  int n0 = bx*64, m0 = by*64;
  float acc[4][8];
  #pragma unroll
  for (int i=0;i<4;i++)
    #pragma unroll
    for (int j=0;j<8;j++) acc[i][j] = 0.f;
  for (int k0=0; k0<K; k0+=16){
    #pragma unroll
    for (int p=0;p<8;p++){
      int idx = tid + p*128;
      int kk = idx & 15, mm = idx >> 4;
      As[kk][mm] = Aa[(size_t)(m0+mm)*K + k0 + kk];
      int kk2 = idx >> 6, nn2 = idx & 63;
      Bs[kk2][nn2] = W[(size_t)(k0+kk2)*N + n0 + nn2];
    }
    __syncthreads();
    #pragma unroll
    for (int kk=0;kk<16;kk++){
      float a[4], bb[8];
      #pragma unroll
      for (int i=0;i<4;i++) a[i] = As[kk][ty*4+i];
      #pragma unroll
      for (int j=0;j<8;j++) bb[j] = Bs[kk][tx*8+j];
      #pragma unroll
      for (int i=0;i<4;i++)
        #pragma unroll
        for (int j=0;j<8;j++) acc[i][j] = fmaf(a[i], bb[j], acc[i][j]);
    }
    __syncthreads();
  }
  #pragma unroll
  for (int i=0;i<4;i++){
    #pragma unroll
    for (int j=0;j<8;j++){
      int mm = m0 + ty*4 + i, nn = n0 + tx*8 + j;
      float v = acc[i][j] + bias[nn];
      if (ACT){ float sg = 1.f/(1.f + expf(-v)); v = v*sg; }
      out[(size_t)mm*N + nn] = v;
    }
  }
}

__global__ __launch_bounds__(256) void logsoftmax_kernel(float* __restrict__ x){
  int g = blockIdx.x*256 + threadIdx.x;
  float v = x[g];
  float mx = v;
  #pragma unroll
  for (int off=16; off>0; off>>=1) mx = fmaxf(mx, __shfl_xor(mx, off, 32));
  float e = expf(v - mx);
  float s = e;
  #pragma unroll
  for (int off=16; off>0; off>>=1) s += __shfl_xor(s, off, 32);
  x[g] = (v - mx) - logf(s);
}

// ---------------- launch ----------------
extern "C" void kernel_launch(void* const* d_in, const int* in_sizes, int n_in,
                              void* d_out, int out_size, void* d_ws, size_t ws_size,
                              hipStream_t stream){
  const float* obs  = (const float*)d_in[0];
  const float* act  = (const float*)d_in[1];
  const int*   dons = (const int*)d_in[2];
  const float* pw1  = (const float*)d_in[3];
  const float* pb1  = (const float*)d_in[4];
  const float* pw2  = (const float*)d_in[5];
  const float* pb2  = (const float*)d_in[6];
  const float* qw1  = (const float*)d_in[7];
  const float* qb1  = (const float*)d_in[8];
  const float* qw2  = (const float*)d_in[9];
  const float* qb2  = (const float*)d_in[10];
  const float* gwih = (const float*)d_in[11];
  const float* gwhh = (const float*)d_in[12];
  const float* gbih = (const float*)d_in[13];
  const float* gbhh = (const float*)d_in[14];
  float* out = (float*)d_out;
  float* ws  = (float*)d_ws;

  size_t off = 0;
  float* gum    = ws + off; off += (size_t)T_*B_*NC_*NK_;     // 1048576
  float* h0     = ws + off; off += (size_t)B_*R_;             // 65536
  float* h1     = ws + off; off += (size_t)B_*R_;
  float* p1     = ws + off; off += (size_t)KS1*B_*H_;         // 1048576
  float* p2     = ws + off; off += (size_t)KS2*B_*H_;         // 1048576
  float* pg     = ws + off; off += (size_t)NSP*B_*NG_;        // 3735552
  float* hidp   = ws + off; off += (size_t)H_*B_*T_;          // 1048576
  int*   idxb   = (int*)(ws + off);

  gumbel_init<<<(T_*B_*NC_*NK_)/256, 256, 0, stream>>>(gum);
  hipMemsetAsync(h0, 0, (size_t)B_*R_*sizeof(float), stream);

  float* hcur = h0; float* hnxt = h1;
  for (int t=0; t<T_; t++){
    mlp1_gemv<<<dim3(4, KS1), 256, 0, stream>>>(pw1, hcur, obs, t, p1);
    mlp2_fused<<<dim3(2, KS2), 256, 0, stream>>>(p1, pb1, pw2, p2);
    sample_kernel<<<B_, 256, 0, stream>>>(p2, pb2, gum, t, out, idxb);
    gru_unified<<<912, 256, 0, stream>>>(gwih, gwhh, hcur, idxb, act, t, pg);
    gate_kernel<<<(B_*R_)/256, 256, 0, stream>>>(pg, gbih, gbhh, hcur, hnxt, dons, t, out);
    float* tmp = hcur; hcur = hnxt; hnxt = tmp;
  }

  gemm_tiled<1><<<dim3(16,16), 128, 0, stream>>>(out + RECS0, qw1, qb1, hidp, 1024, 1024, 4096);
  gemm_tiled<0><<<dim3(16,16), 128, 0, stream>>>(hidp, qw2, qb2, out + PRIOR0, 1024, 1024, 1024);
  logsoftmax_kernel<<<(B_*T_*LAT_)/256, 256, 0, stream>>>(out + PRIOR0);
}

// Round 3
// 6666.153 us; speedup vs baseline: 2.4796x; 2.4796x over previous
//
#include <hip/hip_runtime.h>
#include <stdint.h>

#define B_ 16
#define T_ 64
#define IN_ 1024
#define R_ 4096
#define A_ 18
#define H_ 1024
#define NC_ 32
#define NK_ 32
#define LAT_ 1024
#define NB_ 8
#define BS_ 512
#define FULL_ 5120
#define GIN_ 5138
#define G3_ 1536
#define NG_ 12288   // NB_*G3_

#define FULLS0 0
#define RECS0 5242880            // B*T*FULL
#define POST0 9437184            // + B*T*R
#define PRIOR0 10485760          // + B*T*LAT

#define KS1 20   // posterior mlp layer1 splits: K=5120, chunk 256
#define KS2 64   // posterior mlp layer2 splits: K=1024, chunk 16
#define KC2 16
#define NSP 18   // GRU partial splits: 16 gwih-h + 2 gwhh

// ---------------- threefry2x32 (JAX-exact) ----------------
__device__ __forceinline__ uint32_t rotl32(uint32_t v, int r){ return (v<<r)|(v>>(32-r)); }

__device__ __forceinline__ void tf2x32(uint32_t k0, uint32_t k1, uint32_t x0, uint32_t x1,
                                       uint32_t& o0, uint32_t& o1){
  uint32_t ks0=k0, ks1=k1, ks2=k0^k1^0x1BD11BDAu;
  x0+=ks0; x1+=ks1;
  x0+=x1; x1=rotl32(x1,13); x1^=x0;
  x0+=x1; x1=rotl32(x1,15); x1^=x0;
  x0+=x1; x1=rotl32(x1,26); x1^=x0;
  x0+=x1; x1=rotl32(x1, 6); x1^=x0;
  x0+=ks1; x1+=ks2+1u;
  x0+=x1; x1=rotl32(x1,17); x1^=x0;
  x0+=x1; x1=rotl32(x1,29); x1^=x0;
  x0+=x1; x1=rotl32(x1,16); x1^=x0;
  x0+=x1; x1=rotl32(x1,24); x1^=x0;
  x0+=ks2; x1+=ks0+2u;
  x0+=x1; x1=rotl32(x1,13); x1^=x0;
  x0+=x1; x1=rotl32(x1,15); x1^=x0;
  x0+=x1; x1=rotl32(x1,26); x1^=x0;
  x0+=x1; x1=rotl32(x1, 6); x1^=x0;
  x0+=ks0; x1+=ks1+3u;
  x0+=x1; x1=rotl32(x1,17); x1^=x0;
  x0+=x1; x1=rotl32(x1,29); x1^=x0;
  x0+=x1; x1=rotl32(x1,16); x1^=x0;
  x0+=x1; x1=rotl32(x1,24); x1^=x0;
  x0+=ks1; x1+=ks2+4u;
  x0+=x1; x1=rotl32(x1,13); x1^=x0;
  x0+=x1; x1=rotl32(x1,15); x1^=x0;
  x0+=x1; x1=rotl32(x1,26); x1^=x0;
  x0+=x1; x1=rotl32(x1, 6); x1^=x0;
  x0+=ks2; x1+=ks0+5u;
  o0=x0; o1=x1;
}

__global__ __launch_bounds__(256) void gumbel_init(float* __restrict__ gum){
  int g = blockIdx.x*256 + threadIdx.x;     // 64 * 16384
  int t = g >> 14, i = g & 16383;
  uint32_t k0t, k1t, o0, o1;
  tf2x32(0u, 1u, 0u, (uint32_t)t, k0t, k1t);
  tf2x32(k0t, k1t, 0u, (uint32_t)i, o0, o1);
  uint32_t bits = o0 ^ o1;
  uint32_t fb = (bits >> 9) | 0x3f800000u;
  float f = __uint_as_float(fb) - 1.0f;
  const float tiny = 1.17549435e-38f;
  float u = fmaxf(tiny, f + tiny);
  gum[g] = -logf(-logf(u));
}

// ---------------- fused per-step stream kernel ----------------
// 472 blocks: [0,384): gwih h-part  (n8 x ct3 x ks16, 256-row chunks, 512-col f2 tiles)
//             [384,432): gwhh       (n8 x ct3 x ks2,  256-row chunks)
//             [432,472): mlp1       (ct2 x ks20,      256-row chunks, cols 0..1024)
// Each thread owns 2 columns (float2) over the full 256-row chunk; x staged in LDS.
__global__ __launch_bounds__(256) void fused_stream(const float* __restrict__ gwih,
    const float* __restrict__ gwhh, const float* __restrict__ pw1,
    const float* __restrict__ h, const float* __restrict__ obs, int t,
    float* __restrict__ pg, float* __restrict__ p1){
  __shared__ float xs[256*16];       // 16 KB, layout [kk][m]
  int bid = blockIdx.x, tid = threadIdx.x;
  float a0[16], a1[16];
  #pragma unroll
  for (int m=0;m<16;m++){ a0[m]=0.f; a1[m]=0.f; }

  if (bid < 432){
    // ----- GRU weight streams -----
    int n, ct, ks, slot;
    const float* w;
    if (bid < 384){
      n = bid/48; int r = bid%48; ct = r/16; ks = r%16; slot = ks;
      int k0 = ks*256;
      for (int i = tid; i < 256*16; i += 256){
        int kk = i >> 4, m = i & 15;
        xs[i] = h[m*R_ + k0 + kk];
      }
      w = gwih + ((size_t)n*GIN_ + k0)*G3_ + ct*512 + tid*2;
    } else {
      int q = bid-384; n = q/6; int r = q%6; ct = r/2; ks = r%2; slot = 16+ks;
      int k0 = ks*256;
      for (int i = tid; i < 256*16; i += 256){
        int kk = i >> 4, m = i & 15;
        xs[i] = h[m*R_ + n*BS_ + k0 + kk];
      }
      w = gwhh + ((size_t)n*BS_ + k0)*G3_ + ct*512 + tid*2;
    }
    __syncthreads();
    #pragma unroll 8
    for (int kk=0; kk<256; kk++){
      float2 wv = *(const float2*)w;
      w += G3_;
      const float4* xv = (const float4*)(xs + kk*16);
      #pragma unroll
      for (int q=0;q<4;q++){
        float4 x4 = xv[q];
        a0[q*4+0] = fmaf(x4.x, wv.x, a0[q*4+0]); a1[q*4+0] = fmaf(x4.x, wv.y, a1[q*4+0]);
        a0[q*4+1] = fmaf(x4.y, wv.x, a0[q*4+1]); a1[q*4+1] = fmaf(x4.y, wv.y, a1[q*4+1]);
        a0[q*4+2] = fmaf(x4.z, wv.x, a0[q*4+2]); a1[q*4+2] = fmaf(x4.z, wv.y, a1[q*4+2]);
        a0[q*4+3] = fmaf(x4.w, wv.x, a0[q*4+3]); a1[q*4+3] = fmaf(x4.w, wv.y, a1[q*4+3]);
      }
    }
    float* o = pg + (size_t)slot*B_*NG_ + (size_t)n*G3_ + ct*512 + tid*2;
    #pragma unroll
    for (int m=0;m<16;m++){
      float2 st; st.x=a0[m]; st.y=a1[m];
      *(float2*)(o + (size_t)m*NG_) = st;
    }
  } else {
    // ----- posterior MLP layer 1 -----
    int q = bid-432, ct = q/KS1, ks = q%KS1;
    int k0 = ks*256;
    for (int i = tid; i < 256*16; i += 256){
      int kk = i >> 4, m = i & 15;
      int k = k0 + kk;
      xs[i] = (k < R_) ? h[m*R_ + k] : obs[((m*T_)+t)*IN_ + (k - R_)];
    }
    __syncthreads();
    const float* w = pw1 + (size_t)k0*H_ + ct*512 + tid*2;
    #pragma unroll 8
    for (int kk=0; kk<256; kk++){
      float2 wv = *(const float2*)w;
      w += H_;
      const float4* xv = (const float4*)(xs + kk*16);
      #pragma unroll
      for (int qq=0;qq<4;qq++){
        float4 x4 = xv[qq];
        a0[qq*4+0] = fmaf(x4.x, wv.x, a0[qq*4+0]); a1[qq*4+0] = fmaf(x4.x, wv.y, a1[qq*4+0]);
        a0[qq*4+1] = fmaf(x4.y, wv.x, a0[qq*4+1]); a1[qq*4+1] = fmaf(x4.y, wv.y, a1[qq*4+1]);
        a0[qq*4+2] = fmaf(x4.z, wv.x, a0[qq*4+2]); a1[qq*4+2] = fmaf(x4.z, wv.y, a1[qq*4+2]);
        a0[qq*4+3] = fmaf(x4.w, wv.x, a0[qq*4+3]); a1[qq*4+3] = fmaf(x4.w, wv.y, a1[qq*4+3]);
      }
    }
    float* o = p1 + ((size_t)ks*B_)*H_ + ct*512 + tid*2;
    #pragma unroll
    for (int m=0;m<16;m++){
      float2 st; st.x=a0[m]; st.y=a1[m];
      *(float2*)(o + (size_t)m*H_) = st;
    }
  }
}

// fused: reduce p1 slice + silu -> hidden slice in LDS; then GEMV over pw2 rows
__global__ __launch_bounds__(256) void mlp2_fused(const float* __restrict__ p1,
    const float* __restrict__ pb1, const float* __restrict__ pw2,
    float* __restrict__ p2){
  int ct = blockIdx.x, ks = blockIdx.y, tid = threadIdx.x;
  int k0 = ks*KC2;
  __shared__ float hs[KC2*16];   // [kk][b]
  {
    int k = tid & 15, b = tid >> 4;    // one (k,b) pair per thread
    float v = pb1[k0 + k];
    #pragma unroll
    for (int s=0;s<KS1;s++) v += p1[((size_t)s*B_ + b)*H_ + k0 + k];
    float sg = 1.f/(1.f + expf(-v));
    hs[k*16 + b] = v * sg;
  }
  __syncthreads();
  int col = ct*512 + tid*2;
  float a0[16], a1[16];
  #pragma unroll
  for (int m=0;m<16;m++){ a0[m]=0.f; a1[m]=0.f; }
  const float* w = pw2 + (size_t)k0*H_ + col;
  #pragma unroll
  for (int kk=0; kk<KC2; kk++){
    float2 wv = *(const float2*)w;
    w += H_;
    const float4* xv = (const float4*)(hs + kk*16);
    #pragma unroll
    for (int q=0;q<4;q++){
      float4 x4 = xv[q];
      a0[q*4+0] = fmaf(x4.x, wv.x, a0[q*4+0]); a1[q*4+0] = fmaf(x4.x, wv.y, a1[q*4+0]);
      a0[q*4+1] = fmaf(x4.y, wv.x, a0[q*4+1]); a1[q*4+1] = fmaf(x4.y, wv.y, a1[q*4+1]);
      a0[q*4+2] = fmaf(x4.z, wv.x, a0[q*4+2]); a1[q*4+2] = fmaf(x4.z, wv.y, a1[q*4+2]);
      a0[q*4+3] = fmaf(x4.w, wv.x, a0[q*4+3]); a1[q*4+3] = fmaf(x4.w, wv.y, a1[q*4+3]);
    }
  }
  float* o = p2 + (size_t)ks*B_*H_ + col;
  #pragma unroll
  for (int m=0;m<16;m++){ float2 st; st.x=a0[m]; st.y=a1[m]; *(float2*)(o + (size_t)m*H_) = st; }
}

// reduce logits, gumbel-argmax sample, one-hot into fulls, post log-softmax, idx
__global__ __launch_bounds__(256) void sample_kernel(const float* __restrict__ p2,
    const float* __restrict__ pb2, const float* __restrict__ gum, int t,
    float* __restrict__ dout, int* __restrict__ idxb){
  int b = blockIdx.x, tid = threadIdx.x;
  __shared__ float lg[1024];
  for (int c = tid; c < 1024; c += 256){
    float v = pb2[c];
    #pragma unroll 8
    for (int s=0;s<KS2;s++) v += p2[((size_t)s*B_ + b)*H_ + c];
    lg[c] = v;
  }
  __syncthreads();
  int lane = tid & 31;
  int grp = tid >> 5;    // 8 groups of 32 lanes
  size_t bt = (size_t)b*T_ + t;
  for (int rep=0; rep<4; rep++){
    int nc = rep*8 + grp;
    float l = lg[nc*32 + lane];
    float g = gum[((size_t)t << 14) + (size_t)b*1024 + nc*32 + lane];
    float y = l + g;
    int widx = lane; float wy = y;
    #pragma unroll
    for (int off=16; off>0; off>>=1){
      float oy = __shfl_xor(wy, off, 32);
      int   oi = __shfl_xor(widx, off, 32);
      if (oy > wy || (oy == wy && oi < widx)){ wy = oy; widx = oi; }
    }
    float mx = l;
    #pragma unroll
    for (int off=16; off>0; off>>=1) mx = fmaxf(mx, __shfl_xor(mx, off, 32));
    float e = expf(l - mx);
    float s = e;
    #pragma unroll
    for (int off=16; off>0; off>>=1) s += __shfl_xor(s, off, 32);
    float ls = logf(s);
    dout[POST0 + (bt*NC_ + nc)*NK_ + lane] = (l - mx) - ls;
    dout[FULLS0 + bt*FULL_ + R_ + nc*32 + lane] = (lane == widx) ? 1.0f : 0.0f;
    if (lane == 0) idxb[b*32 + nc] = widx;
  }
}

// reduce pg splits + latent one-hot gather + action rows, apply GRU gates,
// update h, write h_t into recs & fulls
__global__ __launch_bounds__(256) void gate_kernel(const float* __restrict__ pg,
    const float* __restrict__ gwih, const float* __restrict__ gbih,
    const float* __restrict__ gbhh, const float* __restrict__ h_old,
    float* __restrict__ h_new, const int* __restrict__ idxb,
    const float* __restrict__ act, const int* __restrict__ dones, int t,
    float* __restrict__ dout){
  int g = blockIdx.x*256 + threadIdx.x;  // 65536
  int b = g >> 12, j = g & 4095;
  int n = j >> 9, u = j & 511;
  float rx = gbih[n*G3_ + u], zx = gbih[n*G3_ + 512 + u], nx = gbih[n*G3_ + 1024 + u];
  float rh = gbhh[n*G3_ + u], zh = gbhh[n*G3_ + 512 + u], nh = gbhh[n*G3_ + 1024 + u];
  #pragma unroll 4
  for (int s=0;s<16;s++){
    const float* p = pg + ((size_t)s*B_ + b)*NG_ + (size_t)n*G3_;
    rx += p[u]; zx += p[512+u]; nx += p[1024+u];
  }
  #pragma unroll
  for (int s=16;s<18;s++){
    const float* p = pg + ((size_t)s*B_ + b)*NG_ + (size_t)n*G3_;
    rh += p[u]; zh += p[512+u]; nh += p[1024+u];
  }
  // latent one-hot gather: 32 rows per batch elem
  const float* wb = gwih + ((size_t)n*GIN_ + R_)*G3_;
  #pragma unroll 4
  for (int nc=0; nc<32; nc++){
    int idx = idxb[b*32 + nc];
    const float* wr = wb + (size_t)(nc*32 + idx)*G3_;
    rx += wr[u]; zx += wr[512+u]; nx += wr[1024+u];
  }
  // action rows
  const float* wa = gwih + ((size_t)n*GIN_ + R_ + LAT_)*G3_;
  #pragma unroll 2
  for (int a=0; a<A_; a++){
    float av = act[((b*T_)+t)*A_ + a];
    rx = fmaf(av, wa[u], rx); zx = fmaf(av, wa[512+u], zx); nx = fmaf(av, wa[1024+u], nx);
    wa += G3_;
  }
  float rr = 1.f/(1.f + expf(-(rx+rh)));
  float zz = 1.f/(1.f + expf(-(zx+zh)));
  float nn = tanhf(nx + rr*nh);
  float hold = h_old[g];
  float hnew = (1.f - zz)*nn + zz*hold;
  float nd = 1.f - (float)dones[b*T_ + t];
  h_new[g] = hnew * nd;
  size_t bt = (size_t)b*T_ + t;
  dout[FULLS0 + bt*FULL_ + j] = hold;
  dout[RECS0 + bt*(size_t)R_ + j] = hold;
}

// ---------------- prior MLP: K-split tiled GEMM (partials -> reduce) ----------
// 64x64 tile, 256 threads, 4x4 per thread (b128 LDS reads), k-step 32, z-split.
template<int KSPL>
__global__ __launch_bounds__(256) void gemm_ks(const float* __restrict__ Aa,
    const float* __restrict__ W, float* __restrict__ part, int M, int N, int K){
  __shared__ float As[32][68];
  __shared__ float Bs[32][64];
  int bx = blockIdx.x, by = blockIdx.y, bz = blockIdx.z, tid = threadIdx.x;
  int tx = tid & 15, ty = tid >> 4;
  int n0 = bx*64, m0 = by*64;
  int kchunk = K / KSPL;
  int kbeg = bz*kchunk;
  float acc[4][4];
  #pragma unroll
  for (int i=0;i<4;i++)
    #pragma unroll
    for (int j=0;j<4;j++) acc[i][j] = 0.f;
  for (int k0=kbeg; k0<kbeg+kchunk; k0+=32){
    for (int i = tid; i < 2048; i += 256){
      int kk = i & 31, mm = i >> 5;
      As[kk][mm] = Aa[(size_t)(m0+mm)*K + k0 + kk];
      int nn2 = i & 63, kk2 = i >> 6;
      Bs[kk2][nn2] = W[(size_t)(k0+kk2)*N + n0 + nn2];
    }
    __syncthreads();
    #pragma unroll 8
    for (int kk=0;kk<32;kk++){
      float4 a4 = *(const float4*)&As[kk][ty*4];
      float4 b4 = *(const float4*)&Bs[kk][tx*4];
      acc[0][0]=fmaf(a4.x,b4.x,acc[0][0]); acc[0][1]=fmaf(a4.x,b4.y,acc[0][1]);
      acc[0][2]=fmaf(a4.x,b4.z,acc[0][2]); acc[0][3]=fmaf(a4.x,b4.w,acc[0][3]);
      acc[1][0]=fmaf(a4.y,b4.x,acc[1][0]); acc[1][1]=fmaf(a4.y,b4.y,acc[1][1]);
      acc[1][2]=fmaf(a4.y,b4.z,acc[1][2]); acc[1][3]=fmaf(a4.y,b4.w,acc[1][3]);
      acc[2][0]=fmaf(a4.z,b4.x,acc[2][0]); acc[2][1]=fmaf(a4.z,b4.y,acc[2][1]);
      acc[2][2]=fmaf(a4.z,b4.z,acc[2][2]); acc[2][3]=fmaf(a4.z,b4.w,acc[2][3]);
      acc[3][0]=fmaf(a4.w,b4.x,acc[3][0]); acc[3][1]=fmaf(a4.w,b4.y,acc[3][1]);
      acc[3][2]=fmaf(a4.w,b4.z,acc[3][2]); acc[3][3]=fmaf(a4.w,b4.w,acc[3][3]);
    }
    __syncthreads();
  }
  #pragma unroll
  for (int i=0;i<4;i++){
    float4 st; st.x=acc[i][0]; st.y=acc[i][1]; st.z=acc[i][2]; st.w=acc[i][3];
    *(float4*)(part + ((size_t)bz*M + m0 + ty*4 + i)*N + n0 + tx*4) = st;
  }
}

// hidp = silu(part0 + part1 + qb1)
__global__ __launch_bounds__(256) void red_silu(const float* __restrict__ part,
    const float* __restrict__ bias, float* __restrict__ out){
  int g = blockIdx.x*256 + threadIdx.x;   // 1M
  int c = g & 1023;
  float v = part[g] + part[1048576 + g] + bias[c];
  float sg = 1.f/(1.f + expf(-v));
  out[g] = v * sg;
}

// prior logits = part0+part1+qb2 -> log_softmax over 32-lane rows -> out
__global__ __launch_bounds__(256) void lsm_final(const float* __restrict__ part,
    const float* __restrict__ bias, float* __restrict__ x){
  int g = blockIdx.x*256 + threadIdx.x;   // 1M
  int c = g & 1023;
  float v = part[g] + part[1048576 + g] + bias[c];
  float mx = v;
  #pragma unroll
  for (int off=16; off>0; off>>=1) mx = fmaxf(mx, __shfl_xor(mx, off, 32));
  float e = expf(v - mx);
  float s = e;
  #pragma unroll
  for (int off=16; off>0; off>>=1) s += __shfl_xor(s, off, 32);
  x[g] = (v - mx) - logf(s);
}

// ---------------- launch ----------------
extern "C" void kernel_launch(void* const* d_in, const int* in_sizes, int n_in,
                              void* d_out, int out_size, void* d_ws, size_t ws_size,
                              hipStream_t stream){
  const float* obs  = (const float*)d_in[0];
  const float* act  = (const float*)d_in[1];
  const int*   dons = (const int*)d_in[2];
  const float* pw1  = (const float*)d_in[3];
  const float* pb1  = (const float*)d_in[4];
  const float* pw2  = (const float*)d_in[5];
  const float* pb2  = (const float*)d_in[6];
  const float* qw1  = (const float*)d_in[7];
  const float* qb1  = (const float*)d_in[8];
  const float* qw2  = (const float*)d_in[9];
  const float* qb2  = (const float*)d_in[10];
  const float* gwih = (const float*)d_in[11];
  const float* gwhh = (const float*)d_in[12];
  const float* gbih = (const float*)d_in[13];
  const float* gbhh = (const float*)d_in[14];
  float* out = (float*)d_out;
  float* ws  = (float*)d_ws;

  size_t off = 0;
  float* gum    = ws + off; off += (size_t)T_*B_*NC_*NK_;     // 1,048,576
  float* h0     = ws + off; off += (size_t)B_*R_;             // 65,536
  float* h1     = ws + off; off += (size_t)B_*R_;
  float* p1     = ws + off; off += (size_t)KS1*B_*H_;         // 327,680
  float* p2     = ws + off; off += (size_t)KS2*B_*H_;         // 1,048,576
  float* pg     = ws + off; off += (size_t)NSP*B_*NG_;        // 3,538,944 (also gemm partials)
  float* hidp   = ws + off; off += (size_t)H_*B_*T_;          // 1,048,576
  int*   idxb   = (int*)(ws + off);

  gumbel_init<<<(T_*B_*NC_*NK_)/256, 256, 0, stream>>>(gum);
  hipMemsetAsync(h0, 0, (size_t)B_*R_*sizeof(float), stream);

  float* hcur = h0; float* hnxt = h1;
  for (int t=0; t<T_; t++){
    fused_stream<<<472, 256, 0, stream>>>(gwih, gwhh, pw1, hcur, obs, t, pg, p1);
    mlp2_fused<<<dim3(2, KS2), 256, 0, stream>>>(p1, pb1, pw2, p2);
    sample_kernel<<<B_, 256, 0, stream>>>(p2, pb2, gum, t, out, idxb);
    gate_kernel<<<(B_*R_)/256, 256, 0, stream>>>(pg, gwih, gbih, gbhh, hcur, hnxt,
                                                 idxb, act, dons, t, out);
    float* tmp = hcur; hcur = hnxt; hnxt = tmp;
  }

  // prior MLP: recs @ qw1 (K=4096, z=2) -> silu -> @ qw2 (K=1024, z=2) -> lsm
  gemm_ks<2><<<dim3(16,16,2), 256, 0, stream>>>(out + RECS0, qw1, pg, 1024, 1024, 4096);
  red_silu<<<4096, 256, 0, stream>>>(pg, qb1, hidp);
  gemm_ks<2><<<dim3(16,16,2), 256, 0, stream>>>(hidp, qw2, pg, 1024, 1024, 1024);
  lsm_final<<<4096, 256, 0, stream>>>(pg, qb2, out + PRIOR0);
}